// Round 19
// baseline (175.301 us; speedup 1.0000x reference)
//
#include <hip/hip_runtime.h>

#define CH 256

// DPP helper: v += dpp_move(v); bound_ctrl=true => out-of-range lanes read 0.
template <int CTRL>
__device__ __forceinline__ float dppAdd(float v) {
    const int m = __builtin_amdgcn_update_dpp(0, __builtin_bit_cast(int, v), CTRL, 0xf, 0xf, true);
    return v + __builtin_bit_cast(float, m);
}

#define OPAQUE4(v) asm volatile("" : "+v"((v).x), "+v"((v).y), "+v"((v).z), "+v"((v).w))

// bf16 helpers: store with round-to-nearest-even; load is exact (<<16)
__device__ __forceinline__ unsigned short f2bf(float f) {
    unsigned int x = __builtin_bit_cast(unsigned int, f);
    return (unsigned short)((x + 0x7fffu + ((x >> 16) & 1u)) >> 16);
}
__device__ __forceinline__ float bf2f(unsigned short u) {
    return __builtin_bit_cast(float, ((unsigned int)u) << 16);
}

// ---------------- embed + fc_input v3 (FROZEN from round 18): bf16 output
__global__ __launch_bounds__(256) void embed_fc2_kernel(
    const int* __restrict__ x,
    const float* __restrict__ e0a, const float* __restrict__ e1a, const float* __restrict__ e2a,
    const float* __restrict__ Wina, const float* __restrict__ bina, unsigned short* __restrict__ h0a,
    const float* __restrict__ e0b, const float* __restrict__ e1b, const float* __restrict__ e2b,
    const float* __restrict__ Winb, const float* __restrict__ binb, unsigned short* __restrict__ h0b,
    const int blocksPer)
{
    __shared__ __align__(16) float eT[128][32];
    int bid = blockIdx.x;
    const float *e0, *e1, *e2, *Win, *bin;
    unsigned short* h0;
    if (bid < blocksPer) { e0 = e0a; e1 = e1a; e2 = e2a; Win = Wina; bin = bina; h0 = h0a; }
    else { bid -= blocksPer; e0 = e0b; e1 = e1b; e2 = e2b; Win = Winb; bin = binb; h0 = h0b; }

    const int row0 = bid * 32;
    const int t = threadIdx.x;
    const int w = t >> 6, l = t & 63;
    const int r = l & 31;
    const int kcBase = 2 * w + (l >> 5);

#pragma unroll
    for (int j = 0; j < 4; ++j) {
        const int kc = kcBase + 8 * j;
        const int k0 = kc * 4;
        const int row = row0 + r;
        float4 v;
        if (kc < 16)      v = *(const float4*)(e0 + (size_t)x[row * 3 + 0] * 64 + k0);
        else if (kc < 24) v = *(const float4*)(e1 + (size_t)x[row * 3 + 1] * 32 + (k0 - 64));
        else              v = *(const float4*)(e2 + (size_t)x[row * 3 + 2] * 32 + (k0 - 96));
        eT[k0 + 0][r] = v.x; eT[k0 + 1][r] = v.y; eT[k0 + 2][r] = v.z; eT[k0 + 3][r] = v.w;
    }
    __syncthreads();

    const float4 bb = *(const float4*)(bin + l * 4);
    float acc[8][4];
#pragma unroll
    for (int rr = 0; rr < 8; ++rr) {
        acc[rr][0] = bb.x; acc[rr][1] = bb.y; acc[rr][2] = bb.z; acc[rr][3] = bb.w;
    }
#pragma unroll 4
    for (int k = 0; k < 128; ++k) {
        const float4 wv = *(const float4*)(Win + (size_t)k * 256 + l * 4);
        const float4 ea = *(const float4*)&eT[k][w * 8];
        const float4 eb = *(const float4*)&eT[k][w * 8 + 4];
        const float ev[8] = {ea.x, ea.y, ea.z, ea.w, eb.x, eb.y, eb.z, eb.w};
#pragma unroll
        for (int rr = 0; rr < 8; ++rr) {
            acc[rr][0] += ev[rr] * wv.x; acc[rr][1] += ev[rr] * wv.y;
            acc[rr][2] += ev[rr] * wv.z; acc[rr][3] += ev[rr] * wv.w;
        }
    }
#pragma unroll
    for (int rr = 0; rr < 8; ++rr) {
        ushort4 o;
        o.x = f2bf(acc[rr][0]); o.y = f2bf(acc[rr][1]);
        o.z = f2bf(acc[rr][2]); o.w = f2bf(acc[rr][3]);
        *(ushort4*)(h0 + (size_t)(row0 + w * 8 + rr) * 256 + l * 4) = o;
    }
}

// ---------------- fc_out: 16-row register-tiled GEMM, K=256 (round-13 proven)
__global__ __launch_bounds__(128) void fcout_kernel(
    const float* __restrict__ ina, const float* __restrict__ Wa,
    const float* __restrict__ auxa, float* __restrict__ oa,
    const float* __restrict__ inb, const float* __restrict__ Wb,
    const float* __restrict__ auxb, float* __restrict__ ob,
    const int blocksPer, const int nRows)
{
    __shared__ __align__(16) float inT[256][16];
    int bid = blockIdx.x;
    const float *in, *W, *aux; float* outp;
    if (bid < blocksPer) { in = ina; W = Wa; aux = auxa; outp = oa; }
    else { bid -= blocksPer; in = inb; W = Wb; aux = auxb; outp = ob; }

    const int row0 = bid * 16;
    const int t = threadIdx.x;
    const int row = t & 15;
    const int kc0 = t >> 4;

#pragma unroll
    for (int j = 0; j < 8; ++j) {
        const int kc = kc0 + 8 * j;
        const int k0 = kc * 4;
        int r = row0 + row;
        if (r >= nRows) r = nRows - 1;
        const float4 v = *(const float4*)(in + (size_t)r * 256 + k0);
        inT[k0 + 0][row] = v.x; inT[k0 + 1][row] = v.y;
        inT[k0 + 2][row] = v.z; inT[k0 + 3][row] = v.w;
    }
    __syncthreads();

    const int w = t >> 6, l = t & 63;
    const int rg = w * 2 + (l >> 5);
    const int r0 = rg * 4;
    const int cc0 = (l & 31) * 4;

    float acc[4][4];
    const float4 bb = *(const float4*)(aux + cc0);
#pragma unroll
    for (int rr = 0; rr < 4; ++rr) {
        acc[rr][0] = bb.x; acc[rr][1] = bb.y; acc[rr][2] = bb.z; acc[rr][3] = bb.w;
    }

#pragma unroll 4
    for (int k = 0; k < 256; ++k) {
        const float4 wv = *(const float4*)(W + (size_t)k * 128 + cc0);
        const float4 ea = *(const float4*)&inT[k][r0];
        const float ev[4] = {ea.x, ea.y, ea.z, ea.w};
#pragma unroll
        for (int rr = 0; rr < 4; ++rr) {
            acc[rr][0] += ev[rr] * wv.x; acc[rr][1] += ev[rr] * wv.y;
            acc[rr][2] += ev[rr] * wv.z; acc[rr][3] += ev[rr] * wv.w;
        }
    }

#pragma unroll
    for (int rr = 0; rr < 4; ++rr) {
        const int r = row0 + r0 + rr;
        if (r < nRows) {
            *(float4*)(outp + (size_t)r * 128 + cc0) =
                make_float4(acc[rr][0], acc[rr][1], acc[rr][2], acc[rr][3]);
        }
    }
}

// ---------------- integ_fused: mm128 + integ2 in one pass (row-local algebra)
// per 8-row block: S = sim@Ws2c, P = cor@Wc2s (pass 1, regs+LDS);
// T1 = S@Wc2s, T2 = P@Ws2c (pass 2);
// z2sim = c0*sim + c1*P + c2*T1 ; z2cor = c0*cor + c1*S + c2*T2.
// LDS tiles [128][9]: stride-9 pad kills the 32-way transposed-write conflict.
__global__ __launch_bounds__(256) void integ_fused_kernel(
    const float* __restrict__ simO, const float* __restrict__ corO,
    const float* __restrict__ Ws2c, const float* __restrict__ Wc2s,
    const float* __restrict__ a1p, const float* __restrict__ a2p,
    const float* __restrict__ b2p,
    float* __restrict__ outSim, float* __restrict__ outCor)
{
    __shared__ float sT[128][9], cT[128][9], ST[128][9], PT[128][9];
    const int t = threadIdx.x;
    const int row0 = blockIdx.x * 8;        // 750 blocks, 6000 = 750*8 exactly

    // stage simT/corT: thread -> (row = t&7, k-quad = t>>3)
    {
        const int row = t & 7;
        const int k0 = (t >> 3) * 4;        // 0..124
        float4 v = *(const float4*)(simO + (size_t)(row0 + row) * 128 + k0);
        sT[k0 + 0][row] = v.x; sT[k0 + 1][row] = v.y;
        sT[k0 + 2][row] = v.z; sT[k0 + 3][row] = v.w;
        v = *(const float4*)(corO + (size_t)(row0 + row) * 128 + k0);
        cT[k0 + 0][row] = v.x; cT[k0 + 1][row] = v.y;
        cT[k0 + 2][row] = v.z; cT[k0 + 3][row] = v.w;
    }
    __syncthreads();

    const int w = t >> 6, l = t & 63;
    const int r0 = w * 2 + (l >> 5);        // 0..7, one row per thread
    const int cc0 = (l & 31) * 4;

    // pass 1: S = sim@Ws2c, P = cor@Wc2s
    float S[4] = {0.f, 0.f, 0.f, 0.f}, P[4] = {0.f, 0.f, 0.f, 0.f};
#pragma unroll 4
    for (int k = 0; k < 128; ++k) {
        const float4 wS = *(const float4*)(Ws2c + (size_t)k * 128 + cc0);
        const float4 wC = *(const float4*)(Wc2s + (size_t)k * 128 + cc0);
        const float eS = sT[k][r0];         // broadcast within half-wave
        const float eC = cT[k][r0];
        S[0] += eS * wS.x; S[1] += eS * wS.y; S[2] += eS * wS.z; S[3] += eS * wS.w;
        P[0] += eC * wC.x; P[1] += eC * wC.y; P[2] += eC * wC.z; P[3] += eC * wC.w;
    }
#pragma unroll
    for (int i = 0; i < 4; ++i) { ST[cc0 + i][r0] = S[i]; PT[cc0 + i][r0] = P[i]; }
    __syncthreads();

    // pass 2: T1 = S@Wc2s, T2 = P@Ws2c
    float T1[4] = {0.f, 0.f, 0.f, 0.f}, T2[4] = {0.f, 0.f, 0.f, 0.f};
#pragma unroll 4
    for (int k = 0; k < 128; ++k) {
        const float4 wC = *(const float4*)(Wc2s + (size_t)k * 128 + cc0);
        const float4 wS = *(const float4*)(Ws2c + (size_t)k * 128 + cc0);
        const float eS2 = ST[k][r0];
        const float eP  = PT[k][r0];
        T1[0] += eS2 * wC.x; T1[1] += eS2 * wC.y; T1[2] += eS2 * wC.z; T1[3] += eS2 * wC.w;
        T2[0] += eP * wS.x;  T2[1] += eP * wS.y;  T2[2] += eP * wS.z;  T2[3] += eP * wS.w;
    }

    // combine + store
    const float a1 = *a1p, a2 = *a2p, b2 = *b2p;
    const float c0 = 1.f - a2 - b2;
    const float c1 = a2 + b2 * (1.f - a1);
    const float c2 = b2 * a1;
    float4 oS, oC;
    oS.x = c0 * sT[cc0 + 0][r0] + c1 * P[0] + c2 * T1[0];
    oS.y = c0 * sT[cc0 + 1][r0] + c1 * P[1] + c2 * T1[1];
    oS.z = c0 * sT[cc0 + 2][r0] + c1 * P[2] + c2 * T1[2];
    oS.w = c0 * sT[cc0 + 3][r0] + c1 * P[3] + c2 * T1[3];
    oC.x = c0 * cT[cc0 + 0][r0] + c1 * S[0] + c2 * T2[0];
    oC.y = c0 * cT[cc0 + 1][r0] + c1 * S[1] + c2 * T2[1];
    oC.z = c0 * cT[cc0 + 2][r0] + c1 * S[2] + c2 * T2[2];
    oC.w = c0 * cT[cc0 + 3][r0] + c1 * S[3] + c2 * T2[3];
    const size_t idx = (size_t)(row0 + r0) * 128 + cc0;
    *(float4*)(outSim + idx) = oS;
    *(float4*)(outCor + idx) = oC;
}

// ---------------- co-attention aggregation (round-14 4-dot L-phase, FROZEN),
// BF16IN: gather ushort4 (8 B/lane); BF16OUT: write ushort4.
template <int K, bool BF16IN, bool BF16OUT>
__global__ __launch_bounds__(256, 2) void coagg_kernel(
    const void* __restrict__ fa, const int* __restrict__ iDa, const int* __restrict__ iQa,
    void* __restrict__ oa,
    const void* __restrict__ fb, const int* __restrict__ iDb, const int* __restrict__ iQb,
    void* __restrict__ ob,
    const int nPer, const int relu)
{
    __shared__ float sL[4][K][K];
    __shared__ float sAC[4][K][K];
    __shared__ float sAS[4][K][K];
    __shared__ float sw_[4][K], su_[4][K];
    __shared__ __align__(16) float sHsum[4][768];

    const int t = threadIdx.x;
    const int wv = t >> 6, lane = t & 63;
    int n = blockIdx.x * 4 + wv;

    const void* feat; const int* idxD; const int* idxQ; void* outp;
    if (n < nPer) { feat = fa; idxD = iDa; idxQ = iQa; outp = oa; }
    else { n -= nPer; feat = fb; idxD = iDb; idxQ = iQb; outp = ob; }

    float4 d[K], q[K], resid;
    if constexpr (BF16IN) {
        const unsigned short* fpu = (const unsigned short*)feat;
#pragma unroll
        for (int k = 0; k < K; ++k) {
            const int rD = idxD[n * K + k];
            const int rQ = idxQ[n * K + k];
            const ushort4 ud = *(const ushort4*)(fpu + (size_t)rD * 256 + lane * 4);
            const ushort4 uq = *(const ushort4*)(fpu + (size_t)rQ * 256 + lane * 4);
            d[k] = make_float4(bf2f(ud.x), bf2f(ud.y), bf2f(ud.z), bf2f(ud.w));
            q[k] = make_float4(bf2f(uq.x), bf2f(uq.y), bf2f(uq.z), bf2f(uq.w));
        }
        const ushort4 ur = *(const ushort4*)(fpu + (size_t)n * 256 + lane * 4);
        resid = make_float4(bf2f(ur.x), bf2f(ur.y), bf2f(ur.z), bf2f(ur.w));
    } else {
        const float4* fp = (const float4*)feat;
#pragma unroll
        for (int k = 0; k < K; ++k) {
            const int rD = idxD[n * K + k];
            const int rQ = idxQ[n * K + k];
            d[k] = fp[(size_t)rD * 64 + lane];
            q[k] = fp[(size_t)rQ * 64 + lane];
        }
        resid = fp[(size_t)n * 64 + lane];
    }
#pragma unroll
    for (int k = 0; k < K; ++k) { OPAQUE4(d[k]); OPAQUE4(q[k]); }

    // L-phase: 4 dots per reduction group (verified round 14)
#pragma unroll
    for (int k = 0; k < K; ++k) {
        const float4 dd = d[k];
#pragma unroll
        for (int m0 = 0; m0 < K; m0 += 4) {
            const float4 q0 = q[m0];
            float s0 = dd.x * q0.x + dd.y * q0.y + dd.z * q0.z + dd.w * q0.w;
            float s1 = 0.f, s2 = 0.f, s3 = 0.f;
            if (m0 + 1 < K) {
                const float4 qq = q[(m0 + 1 < K) ? m0 + 1 : 0];
                s1 = dd.x * qq.x + dd.y * qq.y + dd.z * qq.z + dd.w * qq.w;
            }
            if (m0 + 2 < K) {
                const float4 qq = q[(m0 + 2 < K) ? m0 + 2 : 0];
                s2 = dd.x * qq.x + dd.y * qq.y + dd.z * qq.z + dd.w * qq.w;
            }
            if (m0 + 3 < K) {
                const float4 qq = q[(m0 + 3 < K) ? m0 + 3 : 0];
                s3 = dd.x * qq.x + dd.y * qq.y + dd.z * qq.z + dd.w * qq.w;
            }
            asm volatile("v_permlane32_swap_b32 %0, %1" : "+v"(s0), "+v"(s1));
            float a = s0 + s1;
            asm volatile("v_permlane32_swap_b32 %0, %1" : "+v"(s2), "+v"(s3));
            float b = s2 + s3;
            asm volatile("v_permlane16_swap_b32 %0, %1" : "+v"(a), "+v"(b));
            float r = a + b;
            r = dppAdd<0x111>(r);
            r = dppAdd<0x112>(r);
            r = dppAdd<0x114>(r);
            r = dppAdd<0x118>(r);
            const int rowid = lane >> 4;
            const int mm = m0 + (((rowid & 1) << 1) | (rowid >> 1));
            if ((lane & 15) == 15 && mm < K) sL[wv][k][mm] = r;
        }
    }

    if (lane < K) {
        float e_[K], mx = -1e30f;
#pragma unroll
        for (int m = 0; m < K; ++m) mx = fmaxf(mx, sL[wv][lane][m]);
        float ssum = 0.f;
#pragma unroll
        for (int m = 0; m < K; ++m) { e_[m] = __expf(sL[wv][lane][m] - mx); ssum += e_[m]; }
        const float inv = 1.f / ssum;
#pragma unroll
        for (int m = 0; m < K; ++m) sAC[wv][lane][m] = e_[m] * inv;
    }
    {
        const int c = lane - 16;
        if (c >= 0 && c < K) {
            float e_[K], mx = -1e30f;
#pragma unroll
            for (int m = 0; m < K; ++m) mx = fmaxf(mx, sL[wv][m][c]);
            float ssum = 0.f;
#pragma unroll
            for (int m = 0; m < K; ++m) { e_[m] = __expf(sL[wv][m][c] - mx); ssum += e_[m]; }
            const float inv = 1.f / ssum;
#pragma unroll
            for (int m = 0; m < K; ++m) sAS[wv][c][m] = e_[m] * inv;
        }
    }
    {
        const int m2 = lane - 32;
        if (m2 >= 0 && m2 < K) {
            float s = 0.f;
#pragma unroll
            for (int k2 = 0; k2 < K; ++k2) s += sAS[wv][k2][m2];
            sw_[wv][m2] = s;
        }
    }
    {
        const int j2 = lane - 48;
        if (j2 >= 0 && j2 < K) {
            float s = 0.f;
#pragma unroll
            for (int m = 0; m < K; ++m) s += sw_[wv][m] * sAC[wv][m][j2];
            su_[wv][j2] = s;
        }
    }

    float4 h0v = make_float4(0.f, 0.f, 0.f, 0.f);
    float4 h1v = make_float4(0.f, 0.f, 0.f, 0.f);
    float4 h2v = make_float4(0.f, 0.f, 0.f, 0.f);
#pragma unroll
    for (int kx = 0; kx < K; ++kx) {
        const float wk = sw_[wv][kx];
        const float uk = su_[wv][kx];
        const float4 qq = q[kx];
        const float4 dd = d[kx];
        h0v.x += qq.x;      h0v.y += qq.y;      h0v.z += qq.z;      h0v.w += qq.w;
        h1v.x += wk * dd.x; h1v.y += wk * dd.y; h1v.z += wk * dd.z; h1v.w += wk * dd.w;
        h2v.x += uk * qq.x; h2v.y += uk * qq.y; h2v.z += uk * qq.z; h2v.w += uk * qq.w;
    }
    ((float4*)&sHsum[wv][0])[lane]       = h0v;
    ((float4*)&sHsum[wv][0])[64 + lane]  = h1v;
    ((float4*)&sHsum[wv][0])[128 + lane] = h2v;

    float ov[4];
#pragma unroll
    for (int i = 0; i < 4; ++i) {
        const int f = lane * 4 + i;
        ov[i] = (sHsum[wv][3 * f] + sHsum[wv][3 * f + 1] + sHsum[wv][3 * f + 2])
                * (1.0f / (3.0f * K));
    }
    float4 o = make_float4(resid.x + ov[0], resid.y + ov[1],
                           resid.z + ov[2], resid.w + ov[3]);
    if (relu) {
        o.x = fmaxf(o.x, 0.f); o.y = fmaxf(o.y, 0.f);
        o.z = fmaxf(o.z, 0.f); o.w = fmaxf(o.w, 0.f);
    }
    if constexpr (BF16OUT) {
        ushort4 ou;
        ou.x = f2bf(o.x); ou.y = f2bf(o.y); ou.z = f2bf(o.z); ou.w = f2bf(o.w);
        *(ushort4*)((unsigned short*)outp + (size_t)n * 256 + lane * 4) = ou;
    } else {
        ((float4*)outp)[(size_t)n * 64 + lane] = o;
    }
}

extern "C" void kernel_launch(void* const* d_in, const int* in_sizes, int n_in,
                              void* d_out, int out_size, void* d_ws, size_t ws_size,
                              hipStream_t stream)
{
    const int* x        = (const int*)d_in[0];
    const int* idx_sim0 = (const int*)d_in[1];
    const int* idx_cor0 = (const int*)d_in[2];
    const int* idx_sim1 = (const int*)d_in[3];
    const int* idx_cor1 = (const int*)d_in[4];
    const float* e0s  = (const float*)d_in[5];
    const float* e1s  = (const float*)d_in[6];
    const float* e2s  = (const float*)d_in[7];
    const float* Wins = (const float*)d_in[8];
    const float* bins = (const float*)d_in[9];
    const float* Wouts= (const float*)d_in[10];
    const float* bouts= (const float*)d_in[11];
    const float* e0c  = (const float*)d_in[12];
    const float* e1c  = (const float*)d_in[13];
    const float* e2c  = (const float*)d_in[14];
    const float* Winc = (const float*)d_in[15];
    const float* binc = (const float*)d_in[16];
    const float* Woutc= (const float*)d_in[17];
    const float* boutc= (const float*)d_in[18];
    const float* Ws2c = (const float*)d_in[19];
    const float* Wc2s = (const float*)d_in[20];
    const float* a1 = (const float*)d_in[21];
    const float* a2 = (const float*)d_in[22];
    const float* b2 = (const float*)d_in[23];

    float* outSim = (float*)d_out;
    float* outCor = outSim + 6000 * 128;

    float* ws = (float*)d_ws;
    const size_t needMerged = (size_t)(2 * 16000 * 256 + 2 * 12000 * 256 + 2 * 6000 * 256 + 4 * 6000 * 128) * 4;
    const bool merged = ws_size >= needMerged;

    const int fcBlocks = 6000 / 16;          // 375 (exact)

    if (merged) {
        // A0/A1 and B0/B1 are bf16 (each in its old f32-sized slot)
        unsigned short* A0 = (unsigned short*)ws;
        unsigned short* A1 = (unsigned short*)(ws + 16000 * 256);
        unsigned short* B0 = (unsigned short*)(ws + 2 * 16000 * 256);
        unsigned short* B1 = (unsigned short*)(ws + 2 * 16000 * 256 + 12000 * 256);
        float* C0 = ws + 2 * 16000 * 256 + 2 * 12000 * 256;
        float* C1 = C0 + 6000 * 256;
        float* simO = C1 + 6000 * 256;
        float* corO = simO + 6000 * 128;

        embed_fc2_kernel<<<1000, 256, 0, stream>>>(x,
            e0s, e1s, e2s, Wins, bins, A0,
            e0c, e1c, e2c, Winc, binc, A1, 500);
        // sim: D=feat[idx_cor], Q=feat[idx_sim]; cor: swapped
        coagg_kernel<10, true, true><<<6000, 256, 0, stream>>>(
            A0, idx_cor0, idx_sim0, B0,
            A1, idx_sim0, idx_cor0, B1, 12000, 1);
        coagg_kernel<5, true, false><<<3000, 256, 0, stream>>>(
            B0, idx_cor1, idx_sim1, C0,
            B1, idx_sim1, idx_cor1, C1, 6000, 0);
        fcout_kernel<<<2 * fcBlocks, 128, 0, stream>>>(
            C0, Wouts, bouts, simO,
            C1, Woutc, boutc, corO, fcBlocks, 6000);
        integ_fused_kernel<<<750, 256, 0, stream>>>(
            simO, corO, Ws2c, Wc2s, a1, a2, b2, outSim, outCor);
    } else {
        unsigned short* A = (unsigned short*)ws;
        unsigned short* B = (unsigned short*)(ws + 16000 * 256);
        float* C = ws + 16000 * 256 + 12000 * 256;
        float* simO = C + 6000 * 256;
        float* corO = simO + 6000 * 128;

        for (int b = 0; b < 2; ++b) {
            const float* e0   = (b == 0) ? e0s : e0c;
            const float* e1   = (b == 0) ? e1s : e1c;
            const float* e2   = (b == 0) ? e2s : e2c;
            const float* Win  = (b == 0) ? Wins : Winc;
            const float* bin  = (b == 0) ? bins : binc;
            const float* Wout = (b == 0) ? Wouts : Woutc;
            const float* bout = (b == 0) ? bouts : boutc;
            const int* iD0 = (b == 0) ? idx_cor0 : idx_sim0;
            const int* iQ0 = (b == 0) ? idx_sim0 : idx_cor0;
            const int* iD1 = (b == 0) ? idx_cor1 : idx_sim1;
            const int* iQ1 = (b == 0) ? idx_sim1 : idx_cor1;
            float* branchOut = (b == 0) ? simO : corO;

            embed_fc2_kernel<<<500, 256, 0, stream>>>(x,
                e0, e1, e2, Win, bin, A,
                e0, e1, e2, Win, bin, A, 500);
            coagg_kernel<10, true, true><<<3000, 256, 0, stream>>>(
                A, iD0, iQ0, B, A, iD0, iQ0, B, 12000, 1);
            coagg_kernel<5, true, false><<<1500, 256, 0, stream>>>(
                B, iD1, iQ1, C, B, iD1, iQ1, C, 6000, 0);
            fcout_kernel<<<fcBlocks, 128, 0, stream>>>(
                C, Wout, bout, branchOut,
                C, Wout, bout, branchOut, fcBlocks, 6000);
        }
        integ_fused_kernel<<<750, 256, 0, stream>>>(
            simO, corO, Ws2c, Wc2s, a1, a2, b2, outSim, outCor);
    }
}

// Round 20
// 150.426 us; speedup vs baseline: 1.1654x; 1.1654x over previous
//
#include <hip/hip_runtime.h>

#define CH 256

// DPP helper: v += dpp_move(v); bound_ctrl=true => out-of-range lanes read 0.
template <int CTRL>
__device__ __forceinline__ float dppAdd(float v) {
    const int m = __builtin_amdgcn_update_dpp(0, __builtin_bit_cast(int, v), CTRL, 0xf, 0xf, true);
    return v + __builtin_bit_cast(float, m);
}

#define OPAQUE4(v) asm volatile("" : "+v"((v).x), "+v"((v).y), "+v"((v).z), "+v"((v).w))

// bf16 helpers: store with round-to-nearest-even; load is exact (<<16)
__device__ __forceinline__ unsigned short f2bf(float f) {
    unsigned int x = __builtin_bit_cast(unsigned int, f);
    return (unsigned short)((x + 0x7fffu + ((x >> 16) & 1u)) >> 16);
}
__device__ __forceinline__ float bf2f(unsigned short u) {
    return __builtin_bit_cast(float, ((unsigned int)u) << 16);
}

// ---------------- embed + fc_input v3 (FROZEN from round 18): bf16 output
__global__ __launch_bounds__(256) void embed_fc2_kernel(
    const int* __restrict__ x,
    const float* __restrict__ e0a, const float* __restrict__ e1a, const float* __restrict__ e2a,
    const float* __restrict__ Wina, const float* __restrict__ bina, unsigned short* __restrict__ h0a,
    const float* __restrict__ e0b, const float* __restrict__ e1b, const float* __restrict__ e2b,
    const float* __restrict__ Winb, const float* __restrict__ binb, unsigned short* __restrict__ h0b,
    const int blocksPer)
{
    __shared__ __align__(16) float eT[128][32];
    int bid = blockIdx.x;
    const float *e0, *e1, *e2, *Win, *bin;
    unsigned short* h0;
    if (bid < blocksPer) { e0 = e0a; e1 = e1a; e2 = e2a; Win = Wina; bin = bina; h0 = h0a; }
    else { bid -= blocksPer; e0 = e0b; e1 = e1b; e2 = e2b; Win = Winb; bin = binb; h0 = h0b; }

    const int row0 = bid * 32;
    const int t = threadIdx.x;
    const int w = t >> 6, l = t & 63;
    const int r = l & 31;
    const int kcBase = 2 * w + (l >> 5);

#pragma unroll
    for (int j = 0; j < 4; ++j) {
        const int kc = kcBase + 8 * j;
        const int k0 = kc * 4;
        const int row = row0 + r;
        float4 v;
        if (kc < 16)      v = *(const float4*)(e0 + (size_t)x[row * 3 + 0] * 64 + k0);
        else if (kc < 24) v = *(const float4*)(e1 + (size_t)x[row * 3 + 1] * 32 + (k0 - 64));
        else              v = *(const float4*)(e2 + (size_t)x[row * 3 + 2] * 32 + (k0 - 96));
        eT[k0 + 0][r] = v.x; eT[k0 + 1][r] = v.y; eT[k0 + 2][r] = v.z; eT[k0 + 3][r] = v.w;
    }
    __syncthreads();

    const float4 bb = *(const float4*)(bin + l * 4);
    float acc[8][4];
#pragma unroll
    for (int rr = 0; rr < 8; ++rr) {
        acc[rr][0] = bb.x; acc[rr][1] = bb.y; acc[rr][2] = bb.z; acc[rr][3] = bb.w;
    }
#pragma unroll 4
    for (int k = 0; k < 128; ++k) {
        const float4 wv = *(const float4*)(Win + (size_t)k * 256 + l * 4);
        const float4 ea = *(const float4*)&eT[k][w * 8];
        const float4 eb = *(const float4*)&eT[k][w * 8 + 4];
        const float ev[8] = {ea.x, ea.y, ea.z, ea.w, eb.x, eb.y, eb.z, eb.w};
#pragma unroll
        for (int rr = 0; rr < 8; ++rr) {
            acc[rr][0] += ev[rr] * wv.x; acc[rr][1] += ev[rr] * wv.y;
            acc[rr][2] += ev[rr] * wv.z; acc[rr][3] += ev[rr] * wv.w;
        }
    }
#pragma unroll
    for (int rr = 0; rr < 8; ++rr) {
        ushort4 o;
        o.x = f2bf(acc[rr][0]); o.y = f2bf(acc[rr][1]);
        o.z = f2bf(acc[rr][2]); o.w = f2bf(acc[rr][3]);
        *(ushort4*)(h0 + (size_t)(row0 + w * 8 + rr) * 256 + l * 4) = o;
    }
}

// ---------------- generic 16-row register-tiled GEMM (round-13/14 proven)
// MODE 0: out = in@W + bias(aux)
// MODE 1: out = c0*aux + c1*aux2 + c2*(in@W)
// MODE 2: out = in@W
template <int KD, int MODE>
__global__ __launch_bounds__(128) void gemm16_kernel(
    const float* __restrict__ ina, const float* __restrict__ Wa,
    const float* __restrict__ auxa, const float* __restrict__ aux2a, float* __restrict__ oa,
    const float* __restrict__ inb, const float* __restrict__ Wb,
    const float* __restrict__ auxb, const float* __restrict__ aux2b, float* __restrict__ ob,
    const int blocksPer, const int nRows,
    const float* __restrict__ a1p, const float* __restrict__ a2p, const float* __restrict__ b2p)
{
    __shared__ __align__(16) float inT[KD][16];
    int bid = blockIdx.x;
    const float *in, *W, *aux, *aux2; float* outp;
    if (bid < blocksPer) { in = ina; W = Wa; aux = auxa; aux2 = aux2a; outp = oa; }
    else { bid -= blocksPer; in = inb; W = Wb; aux = auxb; aux2 = aux2b; outp = ob; }

    const int row0 = bid * 16;
    const int t = threadIdx.x;
    const int row = t & 15;
    const int kc0 = t >> 4;

#pragma unroll
    for (int j = 0; j < KD / 32; ++j) {
        const int kc = kc0 + 8 * j;
        const int k0 = kc * 4;
        int r = row0 + row;
        if (r >= nRows) r = nRows - 1;
        const float4 v = *(const float4*)(in + (size_t)r * KD + k0);
        inT[k0 + 0][row] = v.x; inT[k0 + 1][row] = v.y;
        inT[k0 + 2][row] = v.z; inT[k0 + 3][row] = v.w;
    }
    __syncthreads();

    const int w = t >> 6, l = t & 63;
    const int rg = w * 2 + (l >> 5);
    const int r0 = rg * 4;
    const int cc0 = (l & 31) * 4;

    float acc[4][4];
    if constexpr (MODE == 0) {
        const float4 bb = *(const float4*)(aux + cc0);
#pragma unroll
        for (int rr = 0; rr < 4; ++rr) {
            acc[rr][0] = bb.x; acc[rr][1] = bb.y; acc[rr][2] = bb.z; acc[rr][3] = bb.w;
        }
    } else {
#pragma unroll
        for (int rr = 0; rr < 4; ++rr) acc[rr][0] = acc[rr][1] = acc[rr][2] = acc[rr][3] = 0.f;
    }

#pragma unroll 4
    for (int k = 0; k < KD; ++k) {
        const float4 wv = *(const float4*)(W + (size_t)k * 128 + cc0);
        const float4 ea = *(const float4*)&inT[k][r0];
        const float ev[4] = {ea.x, ea.y, ea.z, ea.w};
#pragma unroll
        for (int rr = 0; rr < 4; ++rr) {
            acc[rr][0] += ev[rr] * wv.x; acc[rr][1] += ev[rr] * wv.y;
            acc[rr][2] += ev[rr] * wv.z; acc[rr][3] += ev[rr] * wv.w;
        }
    }

    float c0 = 0.f, c1 = 0.f, c2 = 0.f;
    if constexpr (MODE == 1) {
        const float a1 = *a1p, a2 = *a2p, b2 = *b2p;
        c0 = 1.f - a2 - b2;
        c1 = a2 + b2 * (1.f - a1);
        c2 = b2 * a1;
    }

#pragma unroll
    for (int rr = 0; rr < 4; ++rr) {
        const int r = row0 + r0 + rr;
        if (r < nRows) {
            float4 o = make_float4(acc[rr][0], acc[rr][1], acc[rr][2], acc[rr][3]);
            if constexpr (MODE == 1) {
                const size_t idx = (size_t)r * 128 + cc0;
                const float4 b1v = *(const float4*)(aux + idx);
                const float4 b2v = *(const float4*)(aux2 + idx);
                o.x = c0 * b1v.x + c1 * b2v.x + c2 * o.x;
                o.y = c0 * b1v.y + c1 * b2v.y + c2 * o.y;
                o.z = c0 * b1v.z + c1 * b2v.z + c2 * o.z;
                o.w = c0 * b1v.w + c1 * b2v.w + c2 * o.w;
            }
            *(float4*)(outp + (size_t)r * 128 + cc0) = o;
        }
    }
}

// ---------------- co-attention aggregation (round-14 4-dot L-phase, FROZEN),
// BF16IN: gather ushort4 (8 B/lane); BF16OUT: write ushort4.
template <int K, bool BF16IN, bool BF16OUT>
__global__ __launch_bounds__(256, 2) void coagg_kernel(
    const void* __restrict__ fa, const int* __restrict__ iDa, const int* __restrict__ iQa,
    void* __restrict__ oa,
    const void* __restrict__ fb, const int* __restrict__ iDb, const int* __restrict__ iQb,
    void* __restrict__ ob,
    const int nPer, const int relu)
{
    __shared__ float sL[4][K][K];
    __shared__ float sAC[4][K][K];
    __shared__ float sAS[4][K][K];
    __shared__ float sw_[4][K], su_[4][K];
    __shared__ __align__(16) float sHsum[4][768];

    const int t = threadIdx.x;
    const int wv = t >> 6, lane = t & 63;
    int n = blockIdx.x * 4 + wv;

    const void* feat; const int* idxD; const int* idxQ; void* outp;
    if (n < nPer) { feat = fa; idxD = iDa; idxQ = iQa; outp = oa; }
    else { n -= nPer; feat = fb; idxD = iDb; idxQ = iQb; outp = ob; }

    float4 d[K], q[K], resid;
    if constexpr (BF16IN) {
        const unsigned short* fpu = (const unsigned short*)feat;
#pragma unroll
        for (int k = 0; k < K; ++k) {
            const int rD = idxD[n * K + k];
            const int rQ = idxQ[n * K + k];
            const ushort4 ud = *(const ushort4*)(fpu + (size_t)rD * 256 + lane * 4);
            const ushort4 uq = *(const ushort4*)(fpu + (size_t)rQ * 256 + lane * 4);
            d[k] = make_float4(bf2f(ud.x), bf2f(ud.y), bf2f(ud.z), bf2f(ud.w));
            q[k] = make_float4(bf2f(uq.x), bf2f(uq.y), bf2f(uq.z), bf2f(uq.w));
        }
        const ushort4 ur = *(const ushort4*)(fpu + (size_t)n * 256 + lane * 4);
        resid = make_float4(bf2f(ur.x), bf2f(ur.y), bf2f(ur.z), bf2f(ur.w));
    } else {
        const float4* fp = (const float4*)feat;
#pragma unroll
        for (int k = 0; k < K; ++k) {
            const int rD = idxD[n * K + k];
            const int rQ = idxQ[n * K + k];
            d[k] = fp[(size_t)rD * 64 + lane];
            q[k] = fp[(size_t)rQ * 64 + lane];
        }
        resid = fp[(size_t)n * 64 + lane];
    }
#pragma unroll
    for (int k = 0; k < K; ++k) { OPAQUE4(d[k]); OPAQUE4(q[k]); }

    // L-phase: 4 dots per reduction group (verified round 14)
#pragma unroll
    for (int k = 0; k < K; ++k) {
        const float4 dd = d[k];
#pragma unroll
        for (int m0 = 0; m0 < K; m0 += 4) {
            const float4 q0 = q[m0];
            float s0 = dd.x * q0.x + dd.y * q0.y + dd.z * q0.z + dd.w * q0.w;
            float s1 = 0.f, s2 = 0.f, s3 = 0.f;
            if (m0 + 1 < K) {
                const float4 qq = q[(m0 + 1 < K) ? m0 + 1 : 0];
                s1 = dd.x * qq.x + dd.y * qq.y + dd.z * qq.z + dd.w * qq.w;
            }
            if (m0 + 2 < K) {
                const float4 qq = q[(m0 + 2 < K) ? m0 + 2 : 0];
                s2 = dd.x * qq.x + dd.y * qq.y + dd.z * qq.z + dd.w * qq.w;
            }
            if (m0 + 3 < K) {
                const float4 qq = q[(m0 + 3 < K) ? m0 + 3 : 0];
                s3 = dd.x * qq.x + dd.y * qq.y + dd.z * qq.z + dd.w * qq.w;
            }
            asm volatile("v_permlane32_swap_b32 %0, %1" : "+v"(s0), "+v"(s1));
            float a = s0 + s1;
            asm volatile("v_permlane32_swap_b32 %0, %1" : "+v"(s2), "+v"(s3));
            float b = s2 + s3;
            asm volatile("v_permlane16_swap_b32 %0, %1" : "+v"(a), "+v"(b));
            float r = a + b;
            r = dppAdd<0x111>(r);
            r = dppAdd<0x112>(r);
            r = dppAdd<0x114>(r);
            r = dppAdd<0x118>(r);
            const int rowid = lane >> 4;
            const int mm = m0 + (((rowid & 1) << 1) | (rowid >> 1));
            if ((lane & 15) == 15 && mm < K) sL[wv][k][mm] = r;
        }
    }

    if (lane < K) {
        float e_[K], mx = -1e30f;
#pragma unroll
        for (int m = 0; m < K; ++m) mx = fmaxf(mx, sL[wv][lane][m]);
        float ssum = 0.f;
#pragma unroll
        for (int m = 0; m < K; ++m) { e_[m] = __expf(sL[wv][lane][m] - mx); ssum += e_[m]; }
        const float inv = 1.f / ssum;
#pragma unroll
        for (int m = 0; m < K; ++m) sAC[wv][lane][m] = e_[m] * inv;
    }
    {
        const int c = lane - 16;
        if (c >= 0 && c < K) {
            float e_[K], mx = -1e30f;
#pragma unroll
            for (int m = 0; m < K; ++m) mx = fmaxf(mx, sL[wv][m][c]);
            float ssum = 0.f;
#pragma unroll
            for (int m = 0; m < K; ++m) { e_[m] = __expf(sL[wv][m][c] - mx); ssum += e_[m]; }
            const float inv = 1.f / ssum;
#pragma unroll
            for (int m = 0; m < K; ++m) sAS[wv][c][m] = e_[m] * inv;
        }
    }
    {
        const int m2 = lane - 32;
        if (m2 >= 0 && m2 < K) {
            float s = 0.f;
#pragma unroll
            for (int k2 = 0; k2 < K; ++k2) s += sAS[wv][k2][m2];
            sw_[wv][m2] = s;
        }
    }
    {
        const int j2 = lane - 48;
        if (j2 >= 0 && j2 < K) {
            float s = 0.f;
#pragma unroll
            for (int m = 0; m < K; ++m) s += sw_[wv][m] * sAC[wv][m][j2];
            su_[wv][j2] = s;
        }
    }

    float4 h0v = make_float4(0.f, 0.f, 0.f, 0.f);
    float4 h1v = make_float4(0.f, 0.f, 0.f, 0.f);
    float4 h2v = make_float4(0.f, 0.f, 0.f, 0.f);
#pragma unroll
    for (int kx = 0; kx < K; ++kx) {
        const float wk = sw_[wv][kx];
        const float uk = su_[wv][kx];
        const float4 qq = q[kx];
        const float4 dd = d[kx];
        h0v.x += qq.x;      h0v.y += qq.y;      h0v.z += qq.z;      h0v.w += qq.w;
        h1v.x += wk * dd.x; h1v.y += wk * dd.y; h1v.z += wk * dd.z; h1v.w += wk * dd.w;
        h2v.x += uk * qq.x; h2v.y += uk * qq.y; h2v.z += uk * qq.z; h2v.w += uk * qq.w;
    }
    ((float4*)&sHsum[wv][0])[lane]       = h0v;
    ((float4*)&sHsum[wv][0])[64 + lane]  = h1v;
    ((float4*)&sHsum[wv][0])[128 + lane] = h2v;

    float ov[4];
#pragma unroll
    for (int i = 0; i < 4; ++i) {
        const int f = lane * 4 + i;
        ov[i] = (sHsum[wv][3 * f] + sHsum[wv][3 * f + 1] + sHsum[wv][3 * f + 2])
                * (1.0f / (3.0f * K));
    }
    float4 o = make_float4(resid.x + ov[0], resid.y + ov[1],
                           resid.z + ov[2], resid.w + ov[3]);
    if (relu) {
        o.x = fmaxf(o.x, 0.f); o.y = fmaxf(o.y, 0.f);
        o.z = fmaxf(o.z, 0.f); o.w = fmaxf(o.w, 0.f);
    }
    if constexpr (BF16OUT) {
        ushort4 ou;
        ou.x = f2bf(o.x); ou.y = f2bf(o.y); ou.z = f2bf(o.z); ou.w = f2bf(o.w);
        *(ushort4*)((unsigned short*)outp + (size_t)n * 256 + lane * 4) = ou;
    } else {
        ((float4*)outp)[(size_t)n * 64 + lane] = o;
    }
}

extern "C" void kernel_launch(void* const* d_in, const int* in_sizes, int n_in,
                              void* d_out, int out_size, void* d_ws, size_t ws_size,
                              hipStream_t stream)
{
    const int* x        = (const int*)d_in[0];
    const int* idx_sim0 = (const int*)d_in[1];
    const int* idx_cor0 = (const int*)d_in[2];
    const int* idx_sim1 = (const int*)d_in[3];
    const int* idx_cor1 = (const int*)d_in[4];
    const float* e0s  = (const float*)d_in[5];
    const float* e1s  = (const float*)d_in[6];
    const float* e2s  = (const float*)d_in[7];
    const float* Wins = (const float*)d_in[8];
    const float* bins = (const float*)d_in[9];
    const float* Wouts= (const float*)d_in[10];
    const float* bouts= (const float*)d_in[11];
    const float* e0c  = (const float*)d_in[12];
    const float* e1c  = (const float*)d_in[13];
    const float* e2c  = (const float*)d_in[14];
    const float* Winc = (const float*)d_in[15];
    const float* binc = (const float*)d_in[16];
    const float* Woutc= (const float*)d_in[17];
    const float* boutc= (const float*)d_in[18];
    const float* Ws2c = (const float*)d_in[19];
    const float* Wc2s = (const float*)d_in[20];
    const float* a1 = (const float*)d_in[21];
    const float* a2 = (const float*)d_in[22];
    const float* b2 = (const float*)d_in[23];

    float* outSim = (float*)d_out;
    float* outCor = outSim + 6000 * 128;

    float* ws = (float*)d_ws;
    const size_t needMerged = (size_t)(2 * 16000 * 256 + 2 * 12000 * 256 + 2 * 6000 * 256 + 4 * 6000 * 128) * 4;
    const bool merged = ws_size >= needMerged;

    const int fcBlocks = 6000 / 16;          // 375 (exact)

    if (merged) {
        // A0/A1 and B0/B1 are bf16 (each in its old f32-sized slot)
        unsigned short* A0 = (unsigned short*)ws;
        unsigned short* A1 = (unsigned short*)(ws + 16000 * 256);
        unsigned short* B0 = (unsigned short*)(ws + 2 * 16000 * 256);
        unsigned short* B1 = (unsigned short*)(ws + 2 * 16000 * 256 + 12000 * 256);
        float* C0 = ws + 2 * 16000 * 256 + 2 * 12000 * 256;
        float* C1 = C0 + 6000 * 256;
        float* simO = C1 + 6000 * 256;
        float* corO = simO + 6000 * 128;
        float* P    = corO + 6000 * 128;
        float* S    = P + 6000 * 128;

        embed_fc2_kernel<<<1000, 256, 0, stream>>>(x,
            e0s, e1s, e2s, Wins, bins, A0,
            e0c, e1c, e2c, Winc, binc, A1, 500);
        // sim: D=feat[idx_cor], Q=feat[idx_sim]; cor: swapped
        coagg_kernel<10, true, true><<<6000, 256, 0, stream>>>(
            A0, idx_cor0, idx_sim0, B0,
            A1, idx_sim0, idx_cor0, B1, 12000, 1);
        coagg_kernel<5, true, false><<<3000, 256, 0, stream>>>(
            B0, idx_cor1, idx_sim1, C0,
            B1, idx_sim1, idx_cor1, C1, 6000, 0);
        gemm16_kernel<256, 0><<<2 * fcBlocks, 128, 0, stream>>>(
            C0, Wouts, bouts, nullptr, simO,
            C1, Woutc, boutc, nullptr, corO, fcBlocks, 6000, a1, a2, b2);
        // P = cor@Wc2s ; S = sim@Ws2c
        gemm16_kernel<128, 2><<<2 * fcBlocks, 128, 0, stream>>>(
            corO, Wc2s, nullptr, nullptr, P,
            simO, Ws2c, nullptr, nullptr, S, fcBlocks, 6000, a1, a2, b2);
        // z2sim = c0*sim + c1*P + c2*(S@Wc2s) ; z2cor = c0*cor + c1*S + c2*(P@Ws2c)
        gemm16_kernel<128, 1><<<2 * fcBlocks, 128, 0, stream>>>(
            S, Wc2s, simO, P, outSim,
            P, Ws2c, corO, S, outCor, fcBlocks, 6000, a1, a2, b2);
    } else {
        unsigned short* A = (unsigned short*)ws;
        unsigned short* B = (unsigned short*)(ws + 16000 * 256);
        float* C = ws + 16000 * 256 + 12000 * 256;
        float* simO = C + 6000 * 256;
        float* corO = simO + 6000 * 128;
        float* P    = corO + 6000 * 128;
        float* S    = P + 6000 * 128;

        for (int b = 0; b < 2; ++b) {
            const float* e0   = (b == 0) ? e0s : e0c;
            const float* e1   = (b == 0) ? e1s : e1c;
            const float* e2   = (b == 0) ? e2s : e2c;
            const float* Win  = (b == 0) ? Wins : Winc;
            const float* bin  = (b == 0) ? bins : binc;
            const float* Wout = (b == 0) ? Wouts : Woutc;
            const float* bout = (b == 0) ? bouts : boutc;
            const int* iD0 = (b == 0) ? idx_cor0 : idx_sim0;
            const int* iQ0 = (b == 0) ? idx_sim0 : idx_cor0;
            const int* iD1 = (b == 0) ? idx_cor1 : idx_sim1;
            const int* iQ1 = (b == 0) ? idx_sim1 : idx_cor1;
            float* branchOut = (b == 0) ? simO : corO;

            embed_fc2_kernel<<<500, 256, 0, stream>>>(x,
                e0, e1, e2, Win, bin, A,
                e0, e1, e2, Win, bin, A, 500);
            coagg_kernel<10, true, true><<<3000, 256, 0, stream>>>(
                A, iD0, iQ0, B, A, iD0, iQ0, B, 12000, 1);
            coagg_kernel<5, true, false><<<1500, 256, 0, stream>>>(
                B, iD1, iQ1, C, B, iD1, iQ1, C, 6000, 0);
            gemm16_kernel<256, 0><<<fcBlocks, 128, 0, stream>>>(
                C, Wout, bout, nullptr, branchOut,
                C, Wout, bout, nullptr, branchOut, fcBlocks, 6000, a1, a2, b2);
        }
        gemm16_kernel<128, 2><<<2 * fcBlocks, 128, 0, stream>>>(
            corO, Wc2s, nullptr, nullptr, P,
            simO, Ws2c, nullptr, nullptr, S, fcBlocks, 6000, a1, a2, b2);
        gemm16_kernel<128, 1><<<2 * fcBlocks, 128, 0, stream>>>(
            S, Wc2s, simO, P, outSim,
            P, Ws2c, corO, S, outCor, fcBlocks, 6000, a1, a2, b2);
    }
}